// Round 16
// baseline (644.866 us; speedup 1.0000x reference)
//
#include <hip/hip_runtime.h>
#include <math.h>

#define TSEQ 512
#define FDIM 64
#define HDIM 128
#define NB   512

#define SR 1.4426950408889634f   // log2(e)   : r,z gates
#define SN 2.8853900817779268f   // 2*log2(e) : n gate

typedef _Float16 f16x8 __attribute__((ext_vector_type(8)));
typedef _Float16 f16x4 __attribute__((ext_vector_type(4)));
typedef __fp16  fp16x2 __attribute__((ext_vector_type(2)));
typedef __attribute__((ext_vector_type(4))) float f32x4;

#define H_ROW 136
#define H_BUF (16 * H_ROW)
#define G_STEP ((size_t)96 * NB)

#define CONS_BLOCKS 32
#define PROD_BLOCKS 224
#define NCHUNK 1024               // 32 t-tiles x 32 batch-tiles

#if __has_builtin(__builtin_amdgcn_mfma_f32_16x16x16f16)
#define HAVE_MFMA16K16 1
__device__ __forceinline__ f32x4 mfma16k16(f16x4 a, f16x4 b, f32x4 c) {
    return __builtin_amdgcn_mfma_f32_16x16x16f16(a, b, c, 0, 0, 0);
}
#elif __has_builtin(__builtin_amdgcn_mfma_f32_16x16x16_f16)
#define HAVE_MFMA16K16 1
__device__ __forceinline__ f32x4 mfma16k16(f16x4 a, f16x4 b, f32x4 c) {
    return __builtin_amdgcn_mfma_f32_16x16x16_f16(a, b, c, 0, 0, 0);
}
#else
#define HAVE_MFMA16K16 0
#endif

__device__ __forceinline__ float exp2_hw(float x) {
#if __has_builtin(__builtin_amdgcn_exp2f)
    return __builtin_amdgcn_exp2f(x);
#else
    return exp2f(x);
#endif
}
__device__ __forceinline__ float fast_tanh(float x) {
    return 1.0f - 2.0f * __builtin_amdgcn_rcpf(1.0f + exp2_hw(SN * x));
}
__device__ __forceinline__ f32x4 mfma16f(f16x8 a, f16x8 b, f32x4 c) {
    return __builtin_amdgcn_mfma_f32_16x16x32_f16(a, b, c, 0, 0, 0);
}

union PU { fp16x2 h2[4]; f16x8 v; };
union GU { uint2 u; _Float16 h[4]; f16x4 v; };

__device__ __forceinline__ f16x8 pack_f16(float4 a, float4 b) {
    PU u;
    u.h2[0] = __builtin_amdgcn_cvt_pkrtz(a.x, a.y);
    u.h2[1] = __builtin_amdgcn_cvt_pkrtz(a.z, a.w);
    u.h2[2] = __builtin_amdgcn_cvt_pkrtz(b.x, b.y);
    u.h2[3] = __builtin_amdgcn_cvt_pkrtz(b.z, b.w);
    return u.v;
}

// Raw barrier: drain LDS, then s_barrier. Global ops stay in flight.
__device__ __forceinline__ void wg_barrier() {
    asm volatile("s_waitcnt lgkmcnt(0)" ::: "memory");
    __builtin_amdgcn_s_barrier();
    asm volatile("" ::: "memory");
}

// ---------------- out finalize: out[b][t] = tanh(sum(pp) + b_out) ---------
__global__ __launch_bounds__(512)
void out_final(const float* __restrict__ pp,
               const float* __restrict__ b_out,
               float* __restrict__ out)
{
    const int t = blockIdx.x;
    const int b = threadIdx.x;
    float acc = b_out[0];
    const float* p = pp + (size_t)t * 32 * NB + b;
    #pragma unroll
    for (int c = 0; c < 32; ++c) acc += p[(size_t)c * NB];
    out[(size_t)b * TSEQ + t] = fast_tanh(acc);
}

// ---------------- fused producer/consumer ----------------------------------
// Blocks 0..31  (consumers): R15 recurrence, 16 batches each; per 12-step
//   group advance a monotone t-tile frontier via ACQUIRE atomic loads.
// Blocks 32..255 (producers): gi_gemm chunks (16t x 16b), chunk index
//   ascending so early t-tiles complete first; per-chunk RELEASE handoff
//   (threadfence + syncthreads + atomicAdd on cnt[t-tile]).
__global__ __launch_bounds__(512, 2)
void gru_fused(const float* __restrict__ x,
               const float* __restrict__ W_ih,
               const float* __restrict__ W_hh,
               const float* __restrict__ b_ih,
               const float* __restrict__ b_hh,
               const float* __restrict__ W_out,
               uint2* __restrict__ gi,
               float* __restrict__ pp,
               int* __restrict__ cnt)
{
    __shared__ __align__(16) unsigned char smem[16 * 1032 * 2 + 32];

    const int tid  = threadIdx.x;
    const int wid  = tid >> 6;
    const int lane = tid & 63;
    const int g4   = lane >> 4;
    const int bcol = lane & 15;

    if (blockIdx.x >= CONS_BLOCKS) {
        // ===================== producer =====================
        _Float16* xt = (_Float16*)smem;                 // [16][1032]
        const int pid = blockIdx.x - CONS_BLOCKS;
        const int w = wid;

        f16x8 WihF[3][2];
        #pragma unroll
        for (int kd = 0; kd < 3; ++kd) {
            const float sc = (kd < 2) ? SR : SN;
            const int g = kd * 128 + w * 16 + bcol;
            #pragma unroll
            for (int kt = 0; kt < 2; ++kt) {
                const float* pw = W_ih + g * FDIM + kt * 32 + g4 * 8;
                f16x8 v;
                #pragma unroll
                for (int e = 0; e < 8; ++e) v[e] = (_Float16)(pw[e] * sc);
                WihF[kd][kt] = v;
            }
        }
        f32x4 biasR, biasZ, biasN;
        #pragma unroll
        for (int i = 0; i < 4; ++i) {
            const int gr = w * 16 + g4 * 4 + i;
            biasR[i] = (b_ih[gr]       + b_hh[gr])       * SR;
            biasZ[i] = (b_ih[128 + gr] + b_hh[128 + gr]) * SR;
            biasN[i] = b_ih[256 + gr] * SN;
        }

        for (int c = pid; c < NCHUNK; c += PROD_BLOCKS) {
            const int tau = c >> 5, bt = c & 31;
            const int b0p = bt * 16, t0 = tau * 16;

            __syncthreads();   // xt reuse guard
            {
                const int bl = tid >> 5, q = tid & 31;
                const float* xp = x + ((size_t)(b0p + bl) * TSEQ + t0) * FDIM;
                _Float16* dst = &xt[bl * 1032];
                #pragma unroll
                for (int j = 0; j < 8; ++j) {
                    float4 v = *(const float4*)(xp + j * 128 + q * 4);
                    union { fp16x2 p[2]; uint2 u; } pu;
                    pu.p[0] = __builtin_amdgcn_cvt_pkrtz(v.x, v.y);
                    pu.p[1] = __builtin_amdgcn_cvt_pkrtz(v.z, v.w);
                    *(uint2*)&dst[j * 128 + q * 4] = pu.u;
                }
            }
            __syncthreads();

            for (int tt = 0; tt < 16; ++tt) {
                const _Float16* xr = &xt[bcol * 1032 + tt * 64];
                f16x8 xf0 = *(const f16x8*)(xr + g4 * 8);
                f16x8 xf1 = *(const f16x8*)(xr + 32 + g4 * 8);

                f32x4 c0 = biasR, c1 = biasZ, c2 = biasN;
                c0 = mfma16f(WihF[0][0], xf0, c0);
                c0 = mfma16f(WihF[0][1], xf1, c0);
                c1 = mfma16f(WihF[1][0], xf0, c1);
                c1 = mfma16f(WihF[1][1], xf1, c1);
                c2 = mfma16f(WihF[2][0], xf0, c2);
                c2 = mfma16f(WihF[2][1], xf1, c2);

                GU g0, g1, g2;
                #pragma unroll
                for (int i = 0; i < 4; ++i) {
                    g0.h[i] = (_Float16)c0[i];
                    g1.h[i] = (_Float16)c1[i];
                    g2.h[i] = (_Float16)c2[i];
                }
                const int t = t0 + tt;
                const size_t base = ((size_t)t * 96 + w * 4 + g4) * NB + (b0p + bcol);
                gi[base]           = g0.u;
                gi[base + 32 * NB] = g1.u;
                gi[base + 64 * NB] = g2.u;
            }
            __threadfence();        // device-scope: make stores visible
            __syncthreads();        // all threads' fences complete
            if (tid == 0) atomicAdd(&cnt[tau], 1);
        }
        return;
    }

    // ===================== consumer =====================
    _Float16* h_s = (_Float16*)smem;                    // [3][16][H_ROW]
    const int b0 = blockIdx.x * 16;

    f16x4 iden;
    #pragma unroll
    for (int e = 0; e < 4; ++e)
        iden[e] = (bcol == g4 * 4 + e) ? (_Float16)1.0f : (_Float16)0.0f;
    const f32x4 zero4 = {0.f, 0.f, 0.f, 0.f};

    f16x8 WhhF[3][4];
    #pragma unroll
    for (int kd = 0; kd < 3; ++kd) {
        const float sc = (kd < 2) ? SR : SN;
        const int g = kd * 128 + wid * 16 + bcol;
        #pragma unroll
        for (int kt = 0; kt < 4; ++kt) {
            const float* pw = W_hh + g * HDIM + kt * 32 + g4 * 8;
            f16x8 v;
            #pragma unroll
            for (int e = 0; e < 8; ++e) v[e] = (_Float16)(pw[e] * sc);
            WhhF[kd][kt] = v;
        }
    }

    f32x4 biasNH;
    float wout_r[4], h_old[4];
    #pragma unroll
    for (int i = 0; i < 4; ++i) {
        const int gr = wid * 16 + g4 * 4 + i;
        biasNH[i] = b_hh[256 + gr] * SN;
        wout_r[i] = W_out[gr];
        h_old[i]  = 0.0f;
    }

    {   // zero h buffer 0
        unsigned* hp = (unsigned*)h_s;
        for (int i = tid; i < H_BUF / 2; i += 512) hp[i] = 0u;
    }

    int done_tile = 0;
#define WAIT_TILES(NEED)                                                      \
    {                                                                         \
        int nd_ = (NEED); if (nd_ > 31) nd_ = 31;                             \
        while (done_tile <= nd_) {                                            \
            while (__hip_atomic_load(&cnt[done_tile], __ATOMIC_ACQUIRE,       \
                                     __HIP_MEMORY_SCOPE_AGENT) < 32)          \
                __builtin_amdgcn_s_sleep(8);                                  \
            ++done_tile;                                                      \
        }                                                                     \
    }

    WAIT_TILES(0)   // slot loads below read t = 0..3

    const uint2* gB = gi + ((size_t)wid * 4 + g4) * NB + (b0 + bcol);
    GU r0s, z0s, n0s, r1s, z1s, n1s, r2s, z2s, n2s, r3s, z3s, n3s;
    r0s.u = gB[0];              z0s.u = gB[32 * NB];          n0s.u = gB[64 * NB];
    r1s.u = gB[1*G_STEP];       z1s.u = gB[1*G_STEP + 32*NB]; n1s.u = gB[1*G_STEP + 64*NB];
    r2s.u = gB[2*G_STEP];       z2s.u = gB[2*G_STEP + 32*NB]; n2s.u = gB[2*G_STEP + 64*NB];
    r3s.u = gB[3*G_STEP];       z3s.u = gB[3*G_STEP + 32*NB]; n3s.u = gB[3*G_STEP + 64*NB];
    const uint2* gPr = gB + 4 * G_STEP;
    const uint2* gPz = gPr + 32 * NB;
    const uint2* gPn = gPr + 64 * NB;

    float* ppp = pp + ((size_t)wid * 4 + g4) * NB + (b0 + bcol);

    const _Float16* hrd = h_s + bcol * H_ROW;
    _Float16*       hwr = h_s + bcol * H_ROW + wid * 16 + g4 * 4;

    __syncthreads();   // prologue barrier

#if HAVE_MFMA16K16
#define INJ(S) mfma16k16(iden, S.v, zero4)
#else
#define INJ(S) (f32x4){(float)S.h[0], (float)S.h[1], (float)S.h[2], (float)S.h[3]}
#endif

#define STEP(RB, WB, SL, RF)                                                  \
{                                                                             \
    f16x8 bh0 = *(const f16x8*)(hrd + (RB) * H_BUF + 0 * 32 + g4 * 8);        \
    f16x8 bh1 = *(const f16x8*)(hrd + (RB) * H_BUF + 1 * 32 + g4 * 8);        \
    f16x8 bh2 = *(const f16x8*)(hrd + (RB) * H_BUF + 2 * 32 + g4 * 8);        \
    f16x8 bh3 = *(const f16x8*)(hrd + (RB) * H_BUF + 3 * 32 + g4 * 8);        \
    f32x4 a0 = INJ(r##SL##s);                                                 \
    f32x4 a1 = INJ(z##SL##s);                                                 \
    f32x4 a2 = INJ(n##SL##s);                                                 \
    if (RF) {                                                                 \
        r##SL##s.u = *gPr; z##SL##s.u = *gPz; n##SL##s.u = *gPn;              \
        gPr += G_STEP; gPz += G_STEP; gPn += G_STEP;                          \
    }                                                                         \
    f32x4 a3 = biasNH;                                                        \
    a0 = mfma16f(WhhF[0][0], bh0, a0);                                        \
    a1 = mfma16f(WhhF[1][0], bh0, a1);                                        \
    a3 = mfma16f(WhhF[2][0], bh0, a3);                                        \
    a0 = mfma16f(WhhF[0][1], bh1, a0);                                        \
    a1 = mfma16f(WhhF[1][1], bh1, a1);                                        \
    a3 = mfma16f(WhhF[2][1], bh1, a3);                                        \
    a0 = mfma16f(WhhF[0][2], bh2, a0);                                        \
    a1 = mfma16f(WhhF[1][2], bh2, a1);                                        \
    a3 = mfma16f(WhhF[2][2], bh2, a3);                                        \
    a0 = mfma16f(WhhF[0][3], bh3, a0);                                        \
    a1 = mfma16f(WhhF[1][3], bh3, a1);                                        \
    a3 = mfma16f(WhhF[2][3], bh3, a3);                                        \
    float psum = 0.0f;                                                        \
    float hn[4];                                                              \
    _Pragma("unroll")                                                         \
    for (int i = 0; i < 4; ++i) {                                             \
        float r = __builtin_amdgcn_rcpf(1.0f + exp2_hw(-a0[i]));              \
        float z = __builtin_amdgcn_rcpf(1.0f + exp2_hw(-a1[i]));              \
        float y = fmaf(r, a3[i], a2[i]);                                      \
        float n = fmaf(-2.0f, __builtin_amdgcn_rcpf(1.0f + exp2_hw(y)), 1.0f);\
        hn[i] = fmaf(z, h_old[i] - n, n);                                     \
        h_old[i] = hn[i];                                                     \
        psum = fmaf(wout_r[i], hn[i], psum);                                  \
    }                                                                         \
    {                                                                         \
        union { fp16x2 p[2]; uint2 u; } hu;                                   \
        hu.p[0] = __builtin_amdgcn_cvt_pkrtz(hn[0], hn[1]);                   \
        hu.p[1] = __builtin_amdgcn_cvt_pkrtz(hn[2], hn[3]);                   \
        *(uint2*)(hwr + (WB) * H_BUF) = hu.u;                                 \
    }                                                                         \
    *ppp = psum;                                                              \
    ppp += 32 * NB;                                                           \
    wg_barrier();                                                             \
}

    // 42 x 12 = 504 steps; refills reach t = s+4 -> frontier (s0+19)>>4
    for (int tt = 0; tt < 42; ++tt) {
        WAIT_TILES((tt * 12 + 19) >> 4)
        STEP(0,1,0,1) STEP(1,2,1,1) STEP(2,0,2,1) STEP(0,1,3,1)
        STEP(1,2,0,1) STEP(2,0,1,1) STEP(0,1,2,1) STEP(1,2,3,1)
        STEP(2,0,0,1) STEP(0,1,1,1) STEP(1,2,2,1) STEP(2,0,3,1)
    }
    // tail: s = 504..511
    WAIT_TILES(31)
    STEP(0,1,0,1) STEP(1,2,1,1) STEP(2,0,2,1) STEP(0,1,3,1)
    STEP(1,2,0,0) STEP(2,0,1,0) STEP(0,1,2,0) STEP(1,2,3,0)

#undef STEP
#undef INJ
#undef WAIT_TILES
}

// ---------------- fallback (no workspace): R9/R15-proven unified kernel ---
__global__ __launch_bounds__(512, 2)
void gru_fb(const float* __restrict__ x,
            const float* __restrict__ W_ih,
            const float* __restrict__ W_hh,
            const float* __restrict__ b_ih,
            const float* __restrict__ b_hh,
            const float* __restrict__ W_out,
            const float* __restrict__ b_out,
            float* __restrict__ out)
{
    const int tid  = threadIdx.x;
    const int wid  = tid >> 6;
    const int lane = tid & 63;
    const int g4   = lane >> 4;
    const int bcol = lane & 15;
    const int b0   = blockIdx.x * 16;

    __shared__ __align__(16) _Float16 h_s[3][16][H_ROW];
    __shared__ __align__(16) float ps_s[3][16][12];

    f16x8 WhhF[3][4];
    f16x8 WihF[3][2];
    #pragma unroll
    for (int kd = 0; kd < 3; ++kd) {
        const float sc = (kd < 2) ? SR : SN;
        const int g = kd * 128 + wid * 16 + bcol;
        #pragma unroll
        for (int kt = 0; kt < 4; ++kt) {
            const float* pw = W_hh + g * HDIM + kt * 32 + g4 * 8;
            f16x8 v;
            #pragma unroll
            for (int e = 0; e < 8; ++e) v[e] = (_Float16)(pw[e] * sc);
            WhhF[kd][kt] = v;
        }
        #pragma unroll
        for (int kt = 0; kt < 2; ++kt) {
            const float* pw = W_ih + g * FDIM + kt * 32 + g4 * 8;
            f16x8 v;
            #pragma unroll
            for (int e = 0; e < 8; ++e) v[e] = (_Float16)(pw[e] * sc);
            WihF[kd][kt] = v;
        }
    }

    f32x4 biasR, biasZ, biasNI, biasNH;
    float wout_r[4], h_old[4];
    #pragma unroll
    for (int i = 0; i < 4; ++i) {
        const int gr = wid * 16 + g4 * 4 + i;
        biasR[i]  = (b_ih[gr]       + b_hh[gr])       * SR;
        biasZ[i]  = (b_ih[128 + gr] + b_hh[128 + gr]) * SR;
        biasNI[i] = b_ih[256 + gr] * SN;
        biasNH[i] = b_hh[256 + gr] * SN;
        wout_r[i] = W_out[gr];
        h_old[i]  = 0.0f;
    }
    const float bout = b_out[0];

    {
        unsigned* hp = (unsigned*)&h_s[0][0][0];
        for (int i = tid; i < H_BUF / 2; i += 512) hp[i] = 0u;
    }

    const float* xb = x + (size_t)(b0 + bcol) * TSEQ * FDIM;
    float4 sA0, sA1, sA2, sA3, sB0, sB1, sB2, sB3;
    sA0 = *(const float4*)(xb + g4 * 8);
    sA1 = *(const float4*)(xb + g4 * 8 + 4);
    sA2 = *(const float4*)(xb + 32 + g4 * 8);
    sA3 = *(const float4*)(xb + 32 + g4 * 8 + 4);
    {
        const float* xp1 = xb + FDIM;
        sB0 = *(const float4*)(xp1 + g4 * 8);
        sB1 = *(const float4*)(xp1 + g4 * 8 + 4);
        sB2 = *(const float4*)(xp1 + 32 + g4 * 8);
        sB3 = *(const float4*)(xp1 + 32 + g4 * 8 + 4);
    }
    f16x8 xf0 = pack_f16(sA0, sA1);
    f16x8 xf1 = pack_f16(sA2, sA3);

    __syncthreads();

    const bool outw = (wid == 0) && (lane < 16);
    float* outp = out + (size_t)(b0 + lane) * TSEQ;
    float o0 = 0.f, o1 = 0.f, o2 = 0.f, o3 = 0.f;
    int rb = 0, wb = 1;

    for (int t = 0; t < TSEQ; t += 4) {
        #pragma unroll
        for (int u = 0; u < 4; ++u) {
            const int s = t + u;

            if (outw && s > 0) {
                f32x4 q0 = *(const f32x4*)&ps_s[rb][lane][0];
                f32x4 q1 = *(const f32x4*)&ps_s[rb][lane][4];
                float sm = (q0[0] + q0[1]) + (q0[2] + q0[3])
                         + (q1[0] + q1[1]) + (q1[2] + q1[3]);
                float val = fast_tanh(sm + bout);
                if (u == 0) {
                    o3 = val;
                    *(float4*)(outp + (t - 4)) = make_float4(o0, o1, o2, o3);
                } else if (u == 1) o0 = val;
                else if (u == 2) o1 = val;
                else o2 = val;
            }

            {
                const int tl = (s + 2 < TSEQ) ? (s + 2) : (TSEQ - 1);
                const float* xp = xb + (size_t)tl * FDIM;
                if ((u & 1) == 0) {
                    sA0 = *(const float4*)(xp + g4 * 8);
                    sA1 = *(const float4*)(xp + g4 * 8 + 4);
                    sA2 = *(const float4*)(xp + 32 + g4 * 8);
                    sA3 = *(const float4*)(xp + 32 + g4 * 8 + 4);
                } else {
                    sB0 = *(const float4*)(xp + g4 * 8);
                    sB1 = *(const float4*)(xp + g4 * 8 + 4);
                    sB2 = *(const float4*)(xp + 32 + g4 * 8);
                    sB3 = *(const float4*)(xp + 32 + g4 * 8 + 4);
                }
            }
            f16x8 bh0 = *(const f16x8*)&h_s[rb][bcol][0 * 32 + g4 * 8];
            f16x8 bh1 = *(const f16x8*)&h_s[rb][bcol][1 * 32 + g4 * 8];
            f16x8 bh2 = *(const f16x8*)&h_s[rb][bcol][2 * 32 + g4 * 8];
            f16x8 bh3 = *(const f16x8*)&h_s[rb][bcol][3 * 32 + g4 * 8];

            f32x4 a0 = biasR, a1 = biasZ, a2 = biasNI, a3 = biasNH;
            a0 = mfma16f(WihF[0][0], xf0, a0);
            a0 = mfma16f(WihF[0][1], xf1, a0);
            a1 = mfma16f(WihF[1][0], xf0, a1);
            a1 = mfma16f(WihF[1][1], xf1, a1);
            a2 = mfma16f(WihF[2][0], xf0, a2);
            a2 = mfma16f(WihF[2][1], xf1, a2);

            a0 = mfma16f(WhhF[0][0], bh0, a0);
            a1 = mfma16f(WhhF[1][0], bh0, a1);
            a3 = mfma16f(WhhF[2][0], bh0, a3);
            a0 = mfma16f(WhhF[0][1], bh1, a0);
            a1 = mfma16f(WhhF[1][1], bh1, a1);
            a3 = mfma16f(WhhF[2][1], bh1, a3);
            a0 = mfma16f(WhhF[0][2], bh2, a0);
            a1 = mfma16f(WhhF[1][2], bh2, a1);
            a3 = mfma16f(WhhF[2][2], bh2, a3);
            a0 = mfma16f(WhhF[0][3], bh3, a0);
            a1 = mfma16f(WhhF[1][3], bh3, a1);
            a3 = mfma16f(WhhF[2][3], bh3, a3);

            float psum = 0.0f;
            _Float16 h16[4];
            #pragma unroll
            for (int i = 0; i < 4; ++i) {
                float r  = __builtin_amdgcn_rcpf(1.0f + exp2_hw(-a0[i]));
                float z  = __builtin_amdgcn_rcpf(1.0f + exp2_hw(-a1[i]));
                float y  = fmaf(r, a3[i], a2[i]);
                float n  = fmaf(-2.0f,
                                __builtin_amdgcn_rcpf(1.0f + exp2_hw(y)), 1.0f);
                float hn = fmaf(z, h_old[i] - n, n);
                h_old[i] = hn;
                h16[i]   = (_Float16)hn;
                psum = fmaf(wout_r[i], hn, psum);
            }

            union { _Float16 h[4]; uint2 u; } hu;
            hu.h[0] = h16[0]; hu.h[1] = h16[1];
            hu.h[2] = h16[2]; hu.h[3] = h16[3];
            *(uint2*)&h_s[wb][bcol][wid * 16 + g4 * 4] = hu.u;

            psum += __shfl_xor(psum, 16);
            psum += __shfl_xor(psum, 32);
            if (lane < 16) ps_s[wb][lane][wid] = psum;

            if ((u & 1) == 0) {
                xf0 = pack_f16(sB0, sB1);
                xf1 = pack_f16(sB2, sB3);
            } else {
                xf0 = pack_f16(sA0, sA1);
                xf1 = pack_f16(sA2, sA3);
            }

            wg_barrier();
            rb = wb; wb = (wb == 2) ? 0 : wb + 1;
        }
    }

    if (outw) {
        f32x4 q0 = *(const f32x4*)&ps_s[2][lane][0];
        f32x4 q1 = *(const f32x4*)&ps_s[2][lane][4];
        float sm = (q0[0] + q0[1]) + (q0[2] + q0[3])
                 + (q1[0] + q1[1]) + (q1[2] + q1[3]);
        o3 = fast_tanh(sm + bout);
        *(float4*)(outp + (TSEQ - 4)) = make_float4(o0, o1, o2, o3);
    }
}

extern "C" void kernel_launch(void* const* d_in, const int* in_sizes, int n_in,
                              void* d_out, int out_size, void* d_ws, size_t ws_size,
                              hipStream_t stream) {
    const float* x     = (const float*)d_in[0];
    const float* W_ih  = (const float*)d_in[1];
    const float* W_hh  = (const float*)d_in[2];
    const float* b_ih  = (const float*)d_in[3];
    const float* b_hh  = (const float*)d_in[4];
    const float* W_out = (const float*)d_in[5];
    const float* b_out = (const float*)d_in[6];
    float* out = (float*)d_out;

    const size_t gi_bytes  = (size_t)TSEQ * NB * 384 * sizeof(_Float16); // 201.3 MB
    const size_t pp_bytes  = (size_t)TSEQ * 32 * NB * sizeof(float);     // 33.6 MB
    const size_t cnt_bytes = 4096;

    if (ws_size >= gi_bytes + pp_bytes + cnt_bytes) {
        uint2* gi = (uint2*)d_ws;
        float* pp = (float*)((char*)d_ws + gi_bytes);
        int*   cnt = (int*)((char*)d_ws + gi_bytes + pp_bytes);
        hipMemsetAsync(cnt, 0, cnt_bytes, stream);
        gru_fused<<<CONS_BLOCKS + PROD_BLOCKS, 512, 0, stream>>>(
            x, W_ih, W_hh, b_ih, b_hh, W_out, gi, pp, cnt);
        out_final<<<TSEQ, NB, 0, stream>>>(pp, b_out, out);
    } else {
        gru_fb<<<32, 512, 0, stream>>>(x, W_ih, W_hh, b_ih, b_hh,
                                       W_out, b_out, out);
    }
}

// Round 17
// 622.968 us; speedup vs baseline: 1.0352x; 1.0352x over previous
//
#include <hip/hip_runtime.h>
#include <math.h>

#define TSEQ 512
#define FDIM 64
#define HDIM 128
#define NB   512

#define SR 1.4426950408889634f   // log2(e)   : r,z gates
#define SN 2.8853900817779268f   // 2*log2(e) : n gate

typedef _Float16 f16x8 __attribute__((ext_vector_type(8)));
typedef _Float16 f16x4 __attribute__((ext_vector_type(4)));
typedef __fp16  fp16x2 __attribute__((ext_vector_type(2)));
typedef __attribute__((ext_vector_type(4))) float f32x4;

#define H_ROW 136
#define H_BUF (16 * H_ROW)
#define G_STEP ((size_t)96 * NB)

#define CONS_BLOCKS 32
#define PROD_BLOCKS 224
#define NCHUNK 1024               // 32 t-tiles x 32 batch-tiles

#if __has_builtin(__builtin_amdgcn_mfma_f32_16x16x16f16)
#define HAVE_MFMA16K16 1
__device__ __forceinline__ f32x4 mfma16k16(f16x4 a, f16x4 b, f32x4 c) {
    return __builtin_amdgcn_mfma_f32_16x16x16f16(a, b, c, 0, 0, 0);
}
#elif __has_builtin(__builtin_amdgcn_mfma_f32_16x16x16_f16)
#define HAVE_MFMA16K16 1
__device__ __forceinline__ f32x4 mfma16k16(f16x4 a, f16x4 b, f32x4 c) {
    return __builtin_amdgcn_mfma_f32_16x16x16_f16(a, b, c, 0, 0, 0);
}
#else
#define HAVE_MFMA16K16 0
#endif

__device__ __forceinline__ float exp2_hw(float x) {
#if __has_builtin(__builtin_amdgcn_exp2f)
    return __builtin_amdgcn_exp2f(x);
#else
    return exp2f(x);
#endif
}
__device__ __forceinline__ float fast_tanh(float x) {
    return 1.0f - 2.0f * __builtin_amdgcn_rcpf(1.0f + exp2_hw(SN * x));
}
__device__ __forceinline__ f32x4 mfma16f(f16x8 a, f16x8 b, f32x4 c) {
    return __builtin_amdgcn_mfma_f32_16x16x32_f16(a, b, c, 0, 0, 0);
}

union PU { fp16x2 h2[4]; f16x8 v; };
union GU { uint2 u; _Float16 h[4]; f16x4 v; };

__device__ __forceinline__ f16x8 pack_f16(float4 a, float4 b) {
    PU u;
    u.h2[0] = __builtin_amdgcn_cvt_pkrtz(a.x, a.y);
    u.h2[1] = __builtin_amdgcn_cvt_pkrtz(a.z, a.w);
    u.h2[2] = __builtin_amdgcn_cvt_pkrtz(b.x, b.y);
    u.h2[3] = __builtin_amdgcn_cvt_pkrtz(b.z, b.w);
    return u.v;
}

// Raw barrier: drain LDS, then s_barrier. Global ops stay in flight.
__device__ __forceinline__ void wg_barrier() {
    asm volatile("s_waitcnt lgkmcnt(0)" ::: "memory");
    __builtin_amdgcn_s_barrier();
    asm volatile("" ::: "memory");
}

// ---------------- out finalize: out[b][t] = tanh(sum(pp) + b_out) ---------
__global__ __launch_bounds__(512)
void out_final(const float* __restrict__ pp,
               const float* __restrict__ b_out,
               float* __restrict__ out)
{
    const int t = blockIdx.x;
    const int b = threadIdx.x;
    float acc = b_out[0];
    const float* p = pp + (size_t)t * 32 * NB + b;
    #pragma unroll
    for (int c = 0; c < 32; ++c) acc += p[(size_t)c * NB];
    out[(size_t)b * TSEQ + t] = fast_tanh(acc);
}

// ---------------- fused producer/consumer ----------------------------------
// Blocks 0..31  (consumers): R15 recurrence; per 12-step group tid0 polls
//   the t-tile counters (ACQUIRE + s_sleep), everyone else waits at
//   __syncthreads -- no 512-thread spin storm (R16's failure mode).
// Blocks 32..255 (producers): gi_gemm chunks, ascending so early t first;
//   per-chunk release: threadfence + syncthreads + atomicAdd(cnt[tau]).
// LDS padded to 56KB/block -> at most 2 blocks/CU (co-location bound).
__global__ __launch_bounds__(512, 2)
void gru_fused(const float* __restrict__ x,
               const float* __restrict__ W_ih,
               const float* __restrict__ W_hh,
               const float* __restrict__ b_ih,
               const float* __restrict__ b_hh,
               const float* __restrict__ W_out,
               uint2* __restrict__ gi,
               float* __restrict__ pp,
               int* __restrict__ cnt)
{
    __shared__ __align__(16) unsigned char smem[57344];   // 56 KB

    const int tid  = threadIdx.x;
    const int wid  = tid >> 6;
    const int lane = tid & 63;
    const int g4   = lane >> 4;
    const int bcol = lane & 15;

    if (blockIdx.x >= CONS_BLOCKS) {
        // ===================== producer =====================
        _Float16* xt = (_Float16*)smem;                 // [16][1032]
        const int pid = blockIdx.x - CONS_BLOCKS;
        const int w = wid;

        f16x8 WihF[3][2];
        #pragma unroll
        for (int kd = 0; kd < 3; ++kd) {
            const float sc = (kd < 2) ? SR : SN;
            const int g = kd * 128 + w * 16 + bcol;
            #pragma unroll
            for (int kt = 0; kt < 2; ++kt) {
                const float* pw = W_ih + g * FDIM + kt * 32 + g4 * 8;
                f16x8 v;
                #pragma unroll
                for (int e = 0; e < 8; ++e) v[e] = (_Float16)(pw[e] * sc);
                WihF[kd][kt] = v;
            }
        }
        f32x4 biasR, biasZ, biasN;
        #pragma unroll
        for (int i = 0; i < 4; ++i) {
            const int gr = w * 16 + g4 * 4 + i;
            biasR[i] = (b_ih[gr]       + b_hh[gr])       * SR;
            biasZ[i] = (b_ih[128 + gr] + b_hh[128 + gr]) * SR;
            biasN[i] = b_ih[256 + gr] * SN;
        }

        for (int c = pid; c < NCHUNK; c += PROD_BLOCKS) {
            const int tau = c >> 5, bt = c & 31;
            const int b0p = bt * 16, t0 = tau * 16;

            __syncthreads();   // xt reuse guard
            {
                const int bl = tid >> 5, q = tid & 31;
                const float* xp = x + ((size_t)(b0p + bl) * TSEQ + t0) * FDIM;
                _Float16* dst = &xt[bl * 1032];
                #pragma unroll
                for (int j = 0; j < 8; ++j) {
                    float4 v = *(const float4*)(xp + j * 128 + q * 4);
                    union { fp16x2 p[2]; uint2 u; } pu;
                    pu.p[0] = __builtin_amdgcn_cvt_pkrtz(v.x, v.y);
                    pu.p[1] = __builtin_amdgcn_cvt_pkrtz(v.z, v.w);
                    *(uint2*)&dst[j * 128 + q * 4] = pu.u;
                }
            }
            __syncthreads();

            for (int tt = 0; tt < 16; ++tt) {
                const _Float16* xr = &xt[bcol * 1032 + tt * 64];
                f16x8 xf0 = *(const f16x8*)(xr + g4 * 8);
                f16x8 xf1 = *(const f16x8*)(xr + 32 + g4 * 8);

                f32x4 c0 = biasR, c1 = biasZ, c2 = biasN;
                c0 = mfma16f(WihF[0][0], xf0, c0);
                c0 = mfma16f(WihF[0][1], xf1, c0);
                c1 = mfma16f(WihF[1][0], xf0, c1);
                c1 = mfma16f(WihF[1][1], xf1, c1);
                c2 = mfma16f(WihF[2][0], xf0, c2);
                c2 = mfma16f(WihF[2][1], xf1, c2);

                GU g0, g1, g2;
                #pragma unroll
                for (int i = 0; i < 4; ++i) {
                    g0.h[i] = (_Float16)c0[i];
                    g1.h[i] = (_Float16)c1[i];
                    g2.h[i] = (_Float16)c2[i];
                }
                const int t = t0 + tt;
                const size_t base = ((size_t)t * 96 + w * 4 + g4) * NB + (b0p + bcol);
                gi[base]           = g0.u;
                gi[base + 32 * NB] = g1.u;
                gi[base + 64 * NB] = g2.u;
            }
            __threadfence();        // device-scope: make stores visible
            __syncthreads();        // all threads' fences complete
            if (tid == 0) atomicAdd(&cnt[tau], 1);
        }
        return;
    }

    // ===================== consumer =====================
    _Float16* h_s = (_Float16*)smem;                    // [3][16][H_ROW]
    const int b0 = blockIdx.x * 16;

    f16x4 iden;
    #pragma unroll
    for (int e = 0; e < 4; ++e)
        iden[e] = (bcol == g4 * 4 + e) ? (_Float16)1.0f : (_Float16)0.0f;
    const f32x4 zero4 = {0.f, 0.f, 0.f, 0.f};

    f16x8 WhhF[3][4];
    #pragma unroll
    for (int kd = 0; kd < 3; ++kd) {
        const float sc = (kd < 2) ? SR : SN;
        const int g = kd * 128 + wid * 16 + bcol;
        #pragma unroll
        for (int kt = 0; kt < 4; ++kt) {
            const float* pw = W_hh + g * HDIM + kt * 32 + g4 * 8;
            f16x8 v;
            #pragma unroll
            for (int e = 0; e < 8; ++e) v[e] = (_Float16)(pw[e] * sc);
            WhhF[kd][kt] = v;
        }
    }

    f32x4 biasNH;
    float wout_r[4], h_old[4];
    #pragma unroll
    for (int i = 0; i < 4; ++i) {
        const int gr = wid * 16 + g4 * 4 + i;
        biasNH[i] = b_hh[256 + gr] * SN;
        wout_r[i] = W_out[gr];
        h_old[i]  = 0.0f;
    }

    {   // zero h buffer 0
        unsigned* hp = (unsigned*)h_s;
        for (int i = tid; i < H_BUF / 2; i += 512) hp[i] = 0u;
    }

    int done_tile = 0;
    // tid0-only polling: ACQUIRE load (invalidates CU-shared caches) +
    // s_sleep; all other threads wait at __syncthreads. Tiles can finish
    // out of order, so confirm each tile done_tile..NEED sequentially.
#define WAIT_TILES(NEED)                                                      \
    {                                                                         \
        int nd_ = (NEED); if (nd_ > 31) nd_ = 31;                             \
        if (done_tile <= nd_) {                                               \
            if (tid == 0) {                                                   \
                for (int j_ = done_tile; j_ <= nd_; ++j_)                     \
                    while (__hip_atomic_load(&cnt[j_], __ATOMIC_ACQUIRE,      \
                                             __HIP_MEMORY_SCOPE_AGENT) < 32)  \
                        __builtin_amdgcn_s_sleep(32);                         \
            }                                                                 \
            __syncthreads();                                                  \
            done_tile = nd_ + 1;                                              \
        }                                                                     \
    }

    WAIT_TILES(0)   // slot loads below read t = 0..3

    const uint2* gB = gi + ((size_t)wid * 4 + g4) * NB + (b0 + bcol);
    GU r0s, z0s, n0s, r1s, z1s, n1s, r2s, z2s, n2s, r3s, z3s, n3s;
    r0s.u = gB[0];              z0s.u = gB[32 * NB];          n0s.u = gB[64 * NB];
    r1s.u = gB[1*G_STEP];       z1s.u = gB[1*G_STEP + 32*NB]; n1s.u = gB[1*G_STEP + 64*NB];
    r2s.u = gB[2*G_STEP];       z2s.u = gB[2*G_STEP + 32*NB]; n2s.u = gB[2*G_STEP + 64*NB];
    r3s.u = gB[3*G_STEP];       z3s.u = gB[3*G_STEP + 32*NB]; n3s.u = gB[3*G_STEP + 64*NB];
    const uint2* gPr = gB + 4 * G_STEP;
    const uint2* gPz = gPr + 32 * NB;
    const uint2* gPn = gPr + 64 * NB;

    float* ppp = pp + ((size_t)wid * 4 + g4) * NB + (b0 + bcol);

    const _Float16* hrd = h_s + bcol * H_ROW;
    _Float16*       hwr = h_s + bcol * H_ROW + wid * 16 + g4 * 4;

    __syncthreads();   // prologue barrier

#if HAVE_MFMA16K16
#define INJ(S) mfma16k16(iden, S.v, zero4)
#else
#define INJ(S) (f32x4){(float)S.h[0], (float)S.h[1], (float)S.h[2], (float)S.h[3]}
#endif

#define STEP(RB, WB, SL, RF)                                                  \
{                                                                             \
    f16x8 bh0 = *(const f16x8*)(hrd + (RB) * H_BUF + 0 * 32 + g4 * 8);        \
    f16x8 bh1 = *(const f16x8*)(hrd + (RB) * H_BUF + 1 * 32 + g4 * 8);        \
    f16x8 bh2 = *(const f16x8*)(hrd + (RB) * H_BUF + 2 * 32 + g4 * 8);        \
    f16x8 bh3 = *(const f16x8*)(hrd + (RB) * H_BUF + 3 * 32 + g4 * 8);        \
    f32x4 a0 = INJ(r##SL##s);                                                 \
    f32x4 a1 = INJ(z##SL##s);                                                 \
    f32x4 a2 = INJ(n##SL##s);                                                 \
    if (RF) {                                                                 \
        r##SL##s.u = *gPr; z##SL##s.u = *gPz; n##SL##s.u = *gPn;              \
        gPr += G_STEP; gPz += G_STEP; gPn += G_STEP;                          \
    }                                                                         \
    f32x4 a3 = biasNH;                                                        \
    a0 = mfma16f(WhhF[0][0], bh0, a0);                                        \
    a1 = mfma16f(WhhF[1][0], bh0, a1);                                        \
    a3 = mfma16f(WhhF[2][0], bh0, a3);                                        \
    a0 = mfma16f(WhhF[0][1], bh1, a0);                                        \
    a1 = mfma16f(WhhF[1][1], bh1, a1);                                        \
    a3 = mfma16f(WhhF[2][1], bh1, a3);                                        \
    a0 = mfma16f(WhhF[0][2], bh2, a0);                                        \
    a1 = mfma16f(WhhF[1][2], bh2, a1);                                        \
    a3 = mfma16f(WhhF[2][2], bh2, a3);                                        \
    a0 = mfma16f(WhhF[0][3], bh3, a0);                                        \
    a1 = mfma16f(WhhF[1][3], bh3, a1);                                        \
    a3 = mfma16f(WhhF[2][3], bh3, a3);                                        \
    float psum = 0.0f;                                                        \
    float hn[4];                                                              \
    _Pragma("unroll")                                                         \
    for (int i = 0; i < 4; ++i) {                                             \
        float r = __builtin_amdgcn_rcpf(1.0f + exp2_hw(-a0[i]));              \
        float z = __builtin_amdgcn_rcpf(1.0f + exp2_hw(-a1[i]));              \
        float y = fmaf(r, a3[i], a2[i]);                                      \
        float n = fmaf(-2.0f, __builtin_amdgcn_rcpf(1.0f + exp2_hw(y)), 1.0f);\
        hn[i] = fmaf(z, h_old[i] - n, n);                                     \
        h_old[i] = hn[i];                                                     \
        psum = fmaf(wout_r[i], hn[i], psum);                                  \
    }                                                                         \
    {                                                                         \
        union { fp16x2 p[2]; uint2 u; } hu;                                   \
        hu.p[0] = __builtin_amdgcn_cvt_pkrtz(hn[0], hn[1]);                   \
        hu.p[1] = __builtin_amdgcn_cvt_pkrtz(hn[2], hn[3]);                   \
        *(uint2*)(hwr + (WB) * H_BUF) = hu.u;                                 \
    }                                                                         \
    *ppp = psum;                                                              \
    ppp += 32 * NB;                                                           \
    wg_barrier();                                                             \
}

    // 42 x 12 = 504 steps; refills reach t = s+4 -> frontier (s0+19)>>4
    for (int tt = 0; tt < 42; ++tt) {
        WAIT_TILES((tt * 12 + 19) >> 4)
        STEP(0,1,0,1) STEP(1,2,1,1) STEP(2,0,2,1) STEP(0,1,3,1)
        STEP(1,2,0,1) STEP(2,0,1,1) STEP(0,1,2,1) STEP(1,2,3,1)
        STEP(2,0,0,1) STEP(0,1,1,1) STEP(1,2,2,1) STEP(2,0,3,1)
    }
    // tail: s = 504..511
    WAIT_TILES(31)
    STEP(0,1,0,1) STEP(1,2,1,1) STEP(2,0,2,1) STEP(0,1,3,1)
    STEP(1,2,0,0) STEP(2,0,1,0) STEP(0,1,2,0) STEP(1,2,3,0)

#undef STEP
#undef INJ
#undef WAIT_TILES
}

// ---------------- fallback (no workspace): R9/R15-proven unified kernel ---
__global__ __launch_bounds__(512, 2)
void gru_fb(const float* __restrict__ x,
            const float* __restrict__ W_ih,
            const float* __restrict__ W_hh,
            const float* __restrict__ b_ih,
            const float* __restrict__ b_hh,
            const float* __restrict__ W_out,
            const float* __restrict__ b_out,
            float* __restrict__ out)
{
    const int tid  = threadIdx.x;
    const int wid  = tid >> 6;
    const int lane = tid & 63;
    const int g4   = lane >> 4;
    const int bcol = lane & 15;
    const int b0   = blockIdx.x * 16;

    __shared__ __align__(16) _Float16 h_s[3][16][H_ROW];
    __shared__ __align__(16) float ps_s[3][16][12];

    f16x8 WhhF[3][4];
    f16x8 WihF[3][2];
    #pragma unroll
    for (int kd = 0; kd < 3; ++kd) {
        const float sc = (kd < 2) ? SR : SN;
        const int g = kd * 128 + wid * 16 + bcol;
        #pragma unroll
        for (int kt = 0; kt < 4; ++kt) {
            const float* pw = W_hh + g * HDIM + kt * 32 + g4 * 8;
            f16x8 v;
            #pragma unroll
            for (int e = 0; e < 8; ++e) v[e] = (_Float16)(pw[e] * sc);
            WhhF[kd][kt] = v;
        }
        #pragma unroll
        for (int kt = 0; kt < 2; ++kt) {
            const float* pw = W_ih + g * FDIM + kt * 32 + g4 * 8;
            f16x8 v;
            #pragma unroll
            for (int e = 0; e < 8; ++e) v[e] = (_Float16)(pw[e] * sc);
            WihF[kd][kt] = v;
        }
    }

    f32x4 biasR, biasZ, biasNI, biasNH;
    float wout_r[4], h_old[4];
    #pragma unroll
    for (int i = 0; i < 4; ++i) {
        const int gr = wid * 16 + g4 * 4 + i;
        biasR[i]  = (b_ih[gr]       + b_hh[gr])       * SR;
        biasZ[i]  = (b_ih[128 + gr] + b_hh[128 + gr]) * SR;
        biasNI[i] = b_ih[256 + gr] * SN;
        biasNH[i] = b_hh[256 + gr] * SN;
        wout_r[i] = W_out[gr];
        h_old[i]  = 0.0f;
    }
    const float bout = b_out[0];

    {
        unsigned* hp = (unsigned*)&h_s[0][0][0];
        for (int i = tid; i < H_BUF / 2; i += 512) hp[i] = 0u;
    }

    const float* xb = x + (size_t)(b0 + bcol) * TSEQ * FDIM;
    float4 sA0, sA1, sA2, sA3, sB0, sB1, sB2, sB3;
    sA0 = *(const float4*)(xb + g4 * 8);
    sA1 = *(const float4*)(xb + g4 * 8 + 4);
    sA2 = *(const float4*)(xb + 32 + g4 * 8);
    sA3 = *(const float4*)(xb + 32 + g4 * 8 + 4);
    {
        const float* xp1 = xb + FDIM;
        sB0 = *(const float4*)(xp1 + g4 * 8);
        sB1 = *(const float4*)(xp1 + g4 * 8 + 4);
        sB2 = *(const float4*)(xp1 + 32 + g4 * 8);
        sB3 = *(const float4*)(xp1 + 32 + g4 * 8 + 4);
    }
    f16x8 xf0 = pack_f16(sA0, sA1);
    f16x8 xf1 = pack_f16(sA2, sA3);

    __syncthreads();

    const bool outw = (wid == 0) && (lane < 16);
    float* outp = out + (size_t)(b0 + lane) * TSEQ;
    float o0 = 0.f, o1 = 0.f, o2 = 0.f, o3 = 0.f;
    int rb = 0, wb = 1;

    for (int t = 0; t < TSEQ; t += 4) {
        #pragma unroll
        for (int u = 0; u < 4; ++u) {
            const int s = t + u;

            if (outw && s > 0) {
                f32x4 q0 = *(const f32x4*)&ps_s[rb][lane][0];
                f32x4 q1 = *(const f32x4*)&ps_s[rb][lane][4];
                float sm = (q0[0] + q0[1]) + (q0[2] + q0[3])
                         + (q1[0] + q1[1]) + (q1[2] + q1[3]);
                float val = fast_tanh(sm + bout);
                if (u == 0) {
                    o3 = val;
                    *(float4*)(outp + (t - 4)) = make_float4(o0, o1, o2, o3);
                } else if (u == 1) o0 = val;
                else if (u == 2) o1 = val;
                else o2 = val;
            }

            {
                const int tl = (s + 2 < TSEQ) ? (s + 2) : (TSEQ - 1);
                const float* xp = xb + (size_t)tl * FDIM;
                if ((u & 1) == 0) {
                    sA0 = *(const float4*)(xp + g4 * 8);
                    sA1 = *(const float4*)(xp + g4 * 8 + 4);
                    sA2 = *(const float4*)(xp + 32 + g4 * 8);
                    sA3 = *(const float4*)(xp + 32 + g4 * 8 + 4);
                } else {
                    sB0 = *(const float4*)(xp + g4 * 8);
                    sB1 = *(const float4*)(xp + g4 * 8 + 4);
                    sB2 = *(const float4*)(xp + 32 + g4 * 8);
                    sB3 = *(const float4*)(xp + 32 + g4 * 8 + 4);
                }
            }
            f16x8 bh0 = *(const f16x8*)&h_s[rb][bcol][0 * 32 + g4 * 8];
            f16x8 bh1 = *(const f16x8*)&h_s[rb][bcol][1 * 32 + g4 * 8];
            f16x8 bh2 = *(const f16x8*)&h_s[rb][bcol][2 * 32 + g4 * 8];
            f16x8 bh3 = *(const f16x8*)&h_s[rb][bcol][3 * 32 + g4 * 8];

            f32x4 a0 = biasR, a1 = biasZ, a2 = biasNI, a3 = biasNH;
            a0 = mfma16f(WihF[0][0], xf0, a0);
            a0 = mfma16f(WihF[0][1], xf1, a0);
            a1 = mfma16f(WihF[1][0], xf0, a1);
            a1 = mfma16f(WihF[1][1], xf1, a1);
            a2 = mfma16f(WihF[2][0], xf0, a2);
            a2 = mfma16f(WihF[2][1], xf1, a2);

            a0 = mfma16f(WhhF[0][0], bh0, a0);
            a1 = mfma16f(WhhF[1][0], bh0, a1);
            a3 = mfma16f(WhhF[2][0], bh0, a3);
            a0 = mfma16f(WhhF[0][1], bh1, a0);
            a1 = mfma16f(WhhF[1][1], bh1, a1);
            a3 = mfma16f(WhhF[2][1], bh1, a3);
            a0 = mfma16f(WhhF[0][2], bh2, a0);
            a1 = mfma16f(WhhF[1][2], bh2, a1);
            a3 = mfma16f(WhhF[2][2], bh2, a3);
            a0 = mfma16f(WhhF[0][3], bh3, a0);
            a1 = mfma16f(WhhF[1][3], bh3, a1);
            a3 = mfma16f(WhhF[2][3], bh3, a3);

            float psum = 0.0f;
            _Float16 h16[4];
            #pragma unroll
            for (int i = 0; i < 4; ++i) {
                float r  = __builtin_amdgcn_rcpf(1.0f + exp2_hw(-a0[i]));
                float z  = __builtin_amdgcn_rcpf(1.0f + exp2_hw(-a1[i]));
                float y  = fmaf(r, a3[i], a2[i]);
                float n  = fmaf(-2.0f,
                                __builtin_amdgcn_rcpf(1.0f + exp2_hw(y)), 1.0f);
                float hn = fmaf(z, h_old[i] - n, n);
                h_old[i] = hn;
                h16[i]   = (_Float16)hn;
                psum = fmaf(wout_r[i], hn, psum);
            }

            union { _Float16 h[4]; uint2 u; } hu;
            hu.h[0] = h16[0]; hu.h[1] = h16[1];
            hu.h[2] = h16[2]; hu.h[3] = h16[3];
            *(uint2*)&h_s[wb][bcol][wid * 16 + g4 * 4] = hu.u;

            psum += __shfl_xor(psum, 16);
            psum += __shfl_xor(psum, 32);
            if (lane < 16) ps_s[wb][lane][wid] = psum;

            if ((u & 1) == 0) {
                xf0 = pack_f16(sB0, sB1);
                xf1 = pack_f16(sB2, sB3);
            } else {
                xf0 = pack_f16(sA0, sA1);
                xf1 = pack_f16(sA2, sA3);
            }

            wg_barrier();
            rb = wb; wb = (wb == 2) ? 0 : wb + 1;
        }
    }

    if (outw) {
        f32x4 q0 = *(const f32x4*)&ps_s[2][lane][0];
        f32x4 q1 = *(const f32x4*)&ps_s[2][lane][4];
        float sm = (q0[0] + q0[1]) + (q0[2] + q0[3])
                 + (q1[0] + q1[1]) + (q1[2] + q1[3]);
        o3 = fast_tanh(sm + bout);
        *(float4*)(outp + (TSEQ - 4)) = make_float4(o0, o1, o2, o3);
    }
}

extern "C" void kernel_launch(void* const* d_in, const int* in_sizes, int n_in,
                              void* d_out, int out_size, void* d_ws, size_t ws_size,
                              hipStream_t stream) {
    const float* x     = (const float*)d_in[0];
    const float* W_ih  = (const float*)d_in[1];
    const float* W_hh  = (const float*)d_in[2];
    const float* b_ih  = (const float*)d_in[3];
    const float* b_hh  = (const float*)d_in[4];
    const float* W_out = (const float*)d_in[5];
    const float* b_out = (const float*)d_in[6];
    float* out = (float*)d_out;

    const size_t gi_bytes  = (size_t)TSEQ * NB * 384 * sizeof(_Float16); // 201.3 MB
    const size_t pp_bytes  = (size_t)TSEQ * 32 * NB * sizeof(float);     // 33.6 MB
    const size_t cnt_bytes = 4096;

    if (ws_size >= gi_bytes + pp_bytes + cnt_bytes) {
        uint2* gi = (uint2*)d_ws;
        float* pp = (float*)((char*)d_ws + gi_bytes);
        int*   cnt = (int*)((char*)d_ws + gi_bytes + pp_bytes);
        hipMemsetAsync(cnt, 0, cnt_bytes, stream);
        gru_fused<<<CONS_BLOCKS + PROD_BLOCKS, 512, 0, stream>>>(
            x, W_ih, W_hh, b_ih, b_hh, W_out, gi, pp, cnt);
        out_final<<<TSEQ, NB, 0, stream>>>(pp, b_out, out);
    } else {
        gru_fb<<<32, 512, 0, stream>>>(x, W_ih, W_hh, b_ih, b_hh,
                                       W_out, b_out, out);
    }
}

// Round 18
// 330.002 us; speedup vs baseline: 1.9541x; 1.8878x over previous
//
#include <hip/hip_runtime.h>
#include <math.h>

#define TSEQ 512
#define FDIM 64
#define HDIM 128
#define NB   512

// prescales folded into weights/biases so activations use raw exp2
#define SR 1.4426950408889634f   // log2(e)   : r,z gates
#define SN 2.8853900817779268f   // 2*log2(e) : n gate

typedef _Float16 f16x8 __attribute__((ext_vector_type(8)));
typedef _Float16 f16x4 __attribute__((ext_vector_type(4)));
typedef __fp16  fp16x2 __attribute__((ext_vector_type(2)));
typedef __attribute__((ext_vector_type(4))) float f32x4;

#define H_ROW 136                 // halves per batch row (+8 pad)
#define H_BUF (16 * H_ROW)
#define G_STEP ((size_t)96 * NB)  // uint2 elements per timestep of gi

#if __has_builtin(__builtin_amdgcn_mfma_f32_16x16x16f16)
#define HAVE_MFMA16K16 1
__device__ __forceinline__ f32x4 mfma16k16(f16x4 a, f16x4 b, f32x4 c) {
    return __builtin_amdgcn_mfma_f32_16x16x16f16(a, b, c, 0, 0, 0);
}
#elif __has_builtin(__builtin_amdgcn_mfma_f32_16x16x16_f16)
#define HAVE_MFMA16K16 1
__device__ __forceinline__ f32x4 mfma16k16(f16x4 a, f16x4 b, f32x4 c) {
    return __builtin_amdgcn_mfma_f32_16x16x16_f16(a, b, c, 0, 0, 0);
}
#else
#define HAVE_MFMA16K16 0
#endif

__device__ __forceinline__ float exp2_hw(float x) {
#if __has_builtin(__builtin_amdgcn_exp2f)
    return __builtin_amdgcn_exp2f(x);
#else
    return exp2f(x);
#endif
}
__device__ __forceinline__ float fast_tanh(float x) {
    return 1.0f - 2.0f * __builtin_amdgcn_rcpf(1.0f + exp2_hw(SN * x));
}
__device__ __forceinline__ f32x4 mfma16f(f16x8 a, f16x8 b, f32x4 c) {
    return __builtin_amdgcn_mfma_f32_16x16x32_f16(a, b, c, 0, 0, 0);
}

union PU { fp16x2 h2[4]; f16x8 v; };
union GU { uint2 u; _Float16 h[4]; f16x4 v; };

__device__ __forceinline__ f16x8 pack_f16(float4 a, float4 b) {
    PU u;
    u.h2[0] = __builtin_amdgcn_cvt_pkrtz(a.x, a.y);
    u.h2[1] = __builtin_amdgcn_cvt_pkrtz(a.z, a.w);
    u.h2[2] = __builtin_amdgcn_cvt_pkrtz(b.x, b.y);
    u.h2[3] = __builtin_amdgcn_cvt_pkrtz(b.z, b.w);
    return u.v;
}

// Raw barrier: drain LDS, then s_barrier. Global ops stay in flight.
__device__ __forceinline__ void wg_barrier() {
    asm volatile("s_waitcnt lgkmcnt(0)" ::: "memory");
    __builtin_amdgcn_s_barrier();
    asm volatile("" ::: "memory");
}

// ---------------- pre-GEMM: gi (fp16, prescaled, biases folded) -----------
__global__ __launch_bounds__(512)
void gi_gemm16(const float* __restrict__ x,
               const float* __restrict__ W_ih,
               const float* __restrict__ b_ih,
               const float* __restrict__ b_hh,
               uint2* __restrict__ gi)
{
    const int tid  = threadIdx.x;
    const int w    = tid >> 6;
    const int lane = tid & 63;
    const int g4   = lane >> 4;
    const int bcol = lane & 15;
    const int b0   = blockIdx.x * 16;
    const int t0   = blockIdx.y * 16;

    __shared__ __align__(16) _Float16 xt[16 * 1032 + 8];

    {
        const int bl = tid >> 5, q = tid & 31;
        const float* xp = x + ((size_t)(b0 + bl) * TSEQ + t0) * FDIM;
        _Float16* dst = &xt[bl * 1032];
        #pragma unroll
        for (int j = 0; j < 8; ++j) {
            float4 v = *(const float4*)(xp + j * 128 + q * 4);
            union { fp16x2 p[2]; uint2 u; } pu;
            pu.p[0] = __builtin_amdgcn_cvt_pkrtz(v.x, v.y);
            pu.p[1] = __builtin_amdgcn_cvt_pkrtz(v.z, v.w);
            *(uint2*)&dst[j * 128 + q * 4] = pu.u;
        }
    }

    f16x8 WihF[3][2];
    #pragma unroll
    for (int kd = 0; kd < 3; ++kd) {
        const float sc = (kd < 2) ? SR : SN;
        const int g = kd * 128 + w * 16 + bcol;
        #pragma unroll
        for (int kt = 0; kt < 2; ++kt) {
            const float* pw = W_ih + g * FDIM + kt * 32 + g4 * 8;
            f16x8 v;
            #pragma unroll
            for (int e = 0; e < 8; ++e) v[e] = (_Float16)(pw[e] * sc);
            WihF[kd][kt] = v;
        }
    }
    f32x4 biasR, biasZ, biasN;
    #pragma unroll
    for (int i = 0; i < 4; ++i) {
        const int gr = w * 16 + g4 * 4 + i;
        biasR[i] = (b_ih[gr]       + b_hh[gr])       * SR;
        biasZ[i] = (b_ih[128 + gr] + b_hh[128 + gr]) * SR;
        biasN[i] = b_ih[256 + gr] * SN;
    }
    __syncthreads();

    for (int tt = 0; tt < 16; ++tt) {
        const _Float16* xr = &xt[bcol * 1032 + tt * 64];
        f16x8 xf0 = *(const f16x8*)(xr + g4 * 8);
        f16x8 xf1 = *(const f16x8*)(xr + 32 + g4 * 8);

        f32x4 c0 = biasR, c1 = biasZ, c2 = biasN;
        c0 = mfma16f(WihF[0][0], xf0, c0);
        c0 = mfma16f(WihF[0][1], xf1, c0);
        c1 = mfma16f(WihF[1][0], xf0, c1);
        c1 = mfma16f(WihF[1][1], xf1, c1);
        c2 = mfma16f(WihF[2][0], xf0, c2);
        c2 = mfma16f(WihF[2][1], xf1, c2);

        GU g0, g1, g2;
        #pragma unroll
        for (int i = 0; i < 4; ++i) {
            g0.h[i] = (_Float16)c0[i];
            g1.h[i] = (_Float16)c1[i];
            g2.h[i] = (_Float16)c2[i];
        }
        const int t = t0 + tt;
        const size_t base = ((size_t)t * 96 + w * 4 + g4) * NB + (b0 + bcol);
        gi[base]           = g0.u;
        gi[base + 32 * NB] = g1.u;
        gi[base + 64 * NB] = g2.u;
    }
}

// ---------------- out finalize: out[b][t] = tanh(sum(pp) + b_out) ---------
__global__ __launch_bounds__(512)
void out_final(const float* __restrict__ pp,
               const float* __restrict__ b_out,
               float* __restrict__ out)
{
    const int t = blockIdx.x;
    const int b = threadIdx.x;
    float acc = b_out[0];
    const float* p = pp + (size_t)t * 32 * NB + b;
    #pragma unroll
    for (int c = 0; c < 32; ++c) acc += p[(size_t)c * NB];
    out[(size_t)b * TSEQ + t] = fast_tanh(acc);
}

// ---------------- recurrence (R15 structure + fused z/n gate algebra) -----
// 32 blocks x 16 batches, 512 threads = 8 waves (2/SIMD).
// Static 12-step unroll (compile-time buffer phases), gi via running
// pointers, identity-MFMA gi inject, one lgkm-only barrier per step.
// Gates: with E=exp2(-a1'), F=exp2(y'),
//   h_new = (h*(F+1) + E*(F-1)) / ((1+E)(F+1))
// -- one shared rcp replaces z's rcp + tanh's rcp (6->5 trans/element).
__global__ __launch_bounds__(512, 2)
void gru_rec(const float* __restrict__ W_hh,
             const float* __restrict__ b_hh,
             const float* __restrict__ W_out,
             const uint2* __restrict__ gi,
             float* __restrict__ pp)
{
    const int tid  = threadIdx.x;
    const int wid  = tid >> 6;
    const int lane = tid & 63;
    const int g4   = lane >> 4;
    const int bcol = lane & 15;
    const int b0   = blockIdx.x * 16;

    __shared__ __align__(16) _Float16 h_s[3][16][H_ROW];

    // identity A-fragment for 16x16x16 inject
    f16x4 iden;
    #pragma unroll
    for (int e = 0; e < 4; ++e)
        iden[e] = (bcol == g4 * 4 + e) ? (_Float16)1.0f : (_Float16)0.0f;
    const f32x4 zero4 = {0.f, 0.f, 0.f, 0.f};

    f16x8 WhhF[3][4];
    #pragma unroll
    for (int kd = 0; kd < 3; ++kd) {
        const float sc = (kd < 2) ? SR : SN;
        const int g = kd * 128 + wid * 16 + bcol;
        #pragma unroll
        for (int kt = 0; kt < 4; ++kt) {
            const float* pw = W_hh + g * HDIM + kt * 32 + g4 * 8;
            f16x8 v;
            #pragma unroll
            for (int e = 0; e < 8; ++e) v[e] = (_Float16)(pw[e] * sc);
            WhhF[kd][kt] = v;
        }
    }

    f32x4 biasNH;
    float wout_r[4], h_old[4];
    #pragma unroll
    for (int i = 0; i < 4; ++i) {
        const int gr = wid * 16 + g4 * 4 + i;
        biasNH[i] = b_hh[256 + gr] * SN;
        wout_r[i] = W_out[gr];
        h_old[i]  = 0.0f;
    }

    {   // zero h buffer 0
        unsigned* hp = (unsigned*)&h_s[0][0][0];
        for (int i = tid; i < H_BUF / 2; i += 512) hp[i] = 0u;
    }

    // ---- gi slots for t=0..3 + running refill pointers (t=4...) ----
    const uint2* gB = gi + ((size_t)wid * 4 + g4) * NB + (b0 + bcol);
    GU r0s, z0s, n0s, r1s, z1s, n1s, r2s, z2s, n2s, r3s, z3s, n3s;
    r0s.u = gB[0];              z0s.u = gB[32 * NB];          n0s.u = gB[64 * NB];
    r1s.u = gB[1*G_STEP];       z1s.u = gB[1*G_STEP + 32*NB]; n1s.u = gB[1*G_STEP + 64*NB];
    r2s.u = gB[2*G_STEP];       z2s.u = gB[2*G_STEP + 32*NB]; n2s.u = gB[2*G_STEP + 64*NB];
    r3s.u = gB[3*G_STEP];       z3s.u = gB[3*G_STEP + 32*NB]; n3s.u = gB[3*G_STEP + 64*NB];
    const uint2* gPr = gB + 4 * G_STEP;
    const uint2* gPz = gPr + 32 * NB;
    const uint2* gPn = gPr + 64 * NB;

    float* ppp = pp + ((size_t)wid * 4 + g4) * NB + (b0 + bcol);

    const _Float16* hrd = &h_s[0][bcol][0];
    _Float16*       hwr = &h_s[0][bcol][wid * 16 + g4 * 4];

    __syncthreads();   // prologue barrier

#if HAVE_MFMA16K16
#define INJ(S) mfma16k16(iden, S.v, zero4)
#else
#define INJ(S) (f32x4){(float)S.h[0], (float)S.h[1], (float)S.h[2], (float)S.h[3]}
#endif

#define STEP(RB, WB, SL, RF)                                                  \
{                                                                             \
    f16x8 bh0 = *(const f16x8*)(hrd + (RB) * H_BUF + 0 * 32 + g4 * 8);        \
    f16x8 bh1 = *(const f16x8*)(hrd + (RB) * H_BUF + 1 * 32 + g4 * 8);        \
    f16x8 bh2 = *(const f16x8*)(hrd + (RB) * H_BUF + 2 * 32 + g4 * 8);        \
    f16x8 bh3 = *(const f16x8*)(hrd + (RB) * H_BUF + 3 * 32 + g4 * 8);        \
    f32x4 a0 = INJ(r##SL##s);                                                 \
    f32x4 a1 = INJ(z##SL##s);                                                 \
    f32x4 a2 = INJ(n##SL##s);                                                 \
    if (RF) {                                                                 \
        r##SL##s.u = *gPr; z##SL##s.u = *gPz; n##SL##s.u = *gPn;              \
        gPr += G_STEP; gPz += G_STEP; gPn += G_STEP;                          \
    }                                                                         \
    f32x4 a3 = biasNH;                                                        \
    a0 = mfma16f(WhhF[0][0], bh0, a0);                                        \
    a1 = mfma16f(WhhF[1][0], bh0, a1);                                        \
    a3 = mfma16f(WhhF[2][0], bh0, a3);                                        \
    a0 = mfma16f(WhhF[0][1], bh1, a0);                                        \
    a1 = mfma16f(WhhF[1][1], bh1, a1);                                        \
    a3 = mfma16f(WhhF[2][1], bh1, a3);                                        \
    a0 = mfma16f(WhhF[0][2], bh2, a0);                                        \
    a1 = mfma16f(WhhF[1][2], bh2, a1);                                        \
    a3 = mfma16f(WhhF[2][2], bh2, a3);                                        \
    a0 = mfma16f(WhhF[0][3], bh3, a0);                                        \
    a1 = mfma16f(WhhF[1][3], bh3, a1);                                        \
    a3 = mfma16f(WhhF[2][3], bh3, a3);                                        \
    float psum = 0.0f;                                                        \
    float hn[4];                                                              \
    _Pragma("unroll")                                                         \
    for (int i = 0; i < 4; ++i) {                                             \
        float Er = exp2_hw(-a0[i]);                                           \
        float r  = __builtin_amdgcn_rcpf(1.0f + Er);                          \
        float y  = fmaf(r, a3[i], a2[i]);                                     \
        float F  = exp2_hw(y);                                                \
        float E  = exp2_hw(-a1[i]);                                           \
        float Fp = F + 1.0f;                                                  \
        float den = __builtin_amdgcn_rcpf(fmaf(E, Fp, Fp));                   \
        hn[i] = fmaf(h_old[i], Fp, E * (F - 1.0f)) * den;                     \
        h_old[i] = hn[i];                                                     \
        psum = fmaf(wout_r[i], hn[i], psum);                                  \
    }                                                                         \
    {                                                                         \
        union { fp16x2 p[2]; uint2 u; } hu;                                   \
        hu.p[0] = __builtin_amdgcn_cvt_pkrtz(hn[0], hn[1]);                   \
        hu.p[1] = __builtin_amdgcn_cvt_pkrtz(hn[2], hn[3]);                   \
        *(uint2*)(hwr + (WB) * H_BUF) = hu.u;                                 \
    }                                                                         \
    *ppp = psum;                                                              \
    ppp += 32 * NB;                                                           \
    wg_barrier();                                                             \
}

    // 42 x 12 = 504 steps with compile-time buffer phases
    for (int tt = 0; tt < 42; ++tt) {
        STEP(0,1,0,1) STEP(1,2,1,1) STEP(2,0,2,1) STEP(0,1,3,1)
        STEP(1,2,0,1) STEP(2,0,1,1) STEP(0,1,2,1) STEP(1,2,3,1)
        STEP(2,0,0,1) STEP(0,1,1,1) STEP(1,2,2,1) STEP(2,0,3,1)
    }
    // tail: s = 504..511 (504 % 3 == 0, 504 % 4 == 0)
    STEP(0,1,0,1) STEP(1,2,1,1) STEP(2,0,2,1) STEP(0,1,3,1)
    STEP(1,2,0,0) STEP(2,0,1,0) STEP(0,1,2,0) STEP(1,2,3,0)

#undef STEP
#undef INJ
}

// ---------------- fallback (no workspace): R9-proven unified kernel -------
__global__ __launch_bounds__(512, 2)
void gru_fb(const float* __restrict__ x,
            const float* __restrict__ W_ih,
            const float* __restrict__ W_hh,
            const float* __restrict__ b_ih,
            const float* __restrict__ b_hh,
            const float* __restrict__ W_out,
            const float* __restrict__ b_out,
            float* __restrict__ out)
{
    const int tid  = threadIdx.x;
    const int wid  = tid >> 6;
    const int lane = tid & 63;
    const int g4   = lane >> 4;
    const int bcol = lane & 15;
    const int b0   = blockIdx.x * 16;

    __shared__ __align__(16) _Float16 h_s[3][16][H_ROW];
    __shared__ __align__(16) float ps_s[3][16][12];

    f16x8 WhhF[3][4];
    f16x8 WihF[3][2];
    #pragma unroll
    for (int kd = 0; kd < 3; ++kd) {
        const float sc = (kd < 2) ? SR : SN;
        const int g = kd * 128 + wid * 16 + bcol;
        #pragma unroll
        for (int kt = 0; kt < 4; ++kt) {
            const float* pw = W_hh + g * HDIM + kt * 32 + g4 * 8;
            f16x8 v;
            #pragma unroll
            for (int e = 0; e < 8; ++e) v[e] = (_Float16)(pw[e] * sc);
            WhhF[kd][kt] = v;
        }
        #pragma unroll
        for (int kt = 0; kt < 2; ++kt) {
            const float* pw = W_ih + g * FDIM + kt * 32 + g4 * 8;
            f16x8 v;
            #pragma unroll
            for (int e = 0; e < 8; ++e) v[e] = (_Float16)(pw[e] * sc);
            WihF[kd][kt] = v;
        }
    }

    f32x4 biasR, biasZ, biasNI, biasNH;
    float wout_r[4], h_old[4];
    #pragma unroll
    for (int i = 0; i < 4; ++i) {
        const int gr = wid * 16 + g4 * 4 + i;
        biasR[i]  = (b_ih[gr]       + b_hh[gr])       * SR;
        biasZ[i]  = (b_ih[128 + gr] + b_hh[128 + gr]) * SR;
        biasNI[i] = b_ih[256 + gr] * SN;
        biasNH[i] = b_hh[256 + gr] * SN;
        wout_r[i] = W_out[gr];
        h_old[i]  = 0.0f;
    }
    const float bout = b_out[0];

    {
        unsigned* hp = (unsigned*)&h_s[0][0][0];
        for (int i = tid; i < H_BUF / 2; i += 512) hp[i] = 0u;
    }

    const float* xb = x + (size_t)(b0 + bcol) * TSEQ * FDIM;
    float4 sA0, sA1, sA2, sA3, sB0, sB1, sB2, sB3;
    sA0 = *(const float4*)(xb + g4 * 8);
    sA1 = *(const float4*)(xb + g4 * 8 + 4);
    sA2 = *(const float4*)(xb + 32 + g4 * 8);
    sA3 = *(const float4*)(xb + 32 + g4 * 8 + 4);
    {
        const float* xp1 = xb + FDIM;
        sB0 = *(const float4*)(xp1 + g4 * 8);
        sB1 = *(const float4*)(xp1 + g4 * 8 + 4);
        sB2 = *(const float4*)(xp1 + 32 + g4 * 8);
        sB3 = *(const float4*)(xp1 + 32 + g4 * 8 + 4);
    }
    f16x8 xf0 = pack_f16(sA0, sA1);
    f16x8 xf1 = pack_f16(sA2, sA3);

    __syncthreads();

    const bool outw = (wid == 0) && (lane < 16);
    float* outp = out + (size_t)(b0 + lane) * TSEQ;
    float o0 = 0.f, o1 = 0.f, o2 = 0.f, o3 = 0.f;
    int rb = 0, wb = 1;

    for (int t = 0; t < TSEQ; t += 4) {
        #pragma unroll
        for (int u = 0; u < 4; ++u) {
            const int s = t + u;

            if (outw && s > 0) {
                f32x4 q0 = *(const f32x4*)&ps_s[rb][lane][0];
                f32x4 q1 = *(const f32x4*)&ps_s[rb][lane][4];
                float sm = (q0[0] + q0[1]) + (q0[2] + q0[3])
                         + (q1[0] + q1[1]) + (q1[2] + q1[3]);
                float val = fast_tanh(sm + bout);
                if (u == 0) {
                    o3 = val;
                    *(float4*)(outp + (t - 4)) = make_float4(o0, o1, o2, o3);
                } else if (u == 1) o0 = val;
                else if (u == 2) o1 = val;
                else o2 = val;
            }

            {
                const int tl = (s + 2 < TSEQ) ? (s + 2) : (TSEQ - 1);
                const float* xp = xb + (size_t)tl * FDIM;
                if ((u & 1) == 0) {
                    sA0 = *(const float4*)(xp + g4 * 8);
                    sA1 = *(const float4*)(xp + g4 * 8 + 4);
                    sA2 = *(const float4*)(xp + 32 + g4 * 8);
                    sA3 = *(const float4*)(xp + 32 + g4 * 8 + 4);
                } else {
                    sB0 = *(const float4*)(xp + g4 * 8);
                    sB1 = *(const float4*)(xp + g4 * 8 + 4);
                    sB2 = *(const float4*)(xp + 32 + g4 * 8);
                    sB3 = *(const float4*)(xp + 32 + g4 * 8 + 4);
                }
            }
            f16x8 bh0 = *(const f16x8*)&h_s[rb][bcol][0 * 32 + g4 * 8];
            f16x8 bh1 = *(const f16x8*)&h_s[rb][bcol][1 * 32 + g4 * 8];
            f16x8 bh2 = *(const f16x8*)&h_s[rb][bcol][2 * 32 + g4 * 8];
            f16x8 bh3 = *(const f16x8*)&h_s[rb][bcol][3 * 32 + g4 * 8];

            f32x4 a0 = biasR, a1 = biasZ, a2 = biasNI, a3 = biasNH;
            a0 = mfma16f(WihF[0][0], xf0, a0);
            a0 = mfma16f(WihF[0][1], xf1, a0);
            a1 = mfma16f(WihF[1][0], xf0, a1);
            a1 = mfma16f(WihF[1][1], xf1, a1);
            a2 = mfma16f(WihF[2][0], xf0, a2);
            a2 = mfma16f(WihF[2][1], xf1, a2);

            a0 = mfma16f(WhhF[0][0], bh0, a0);
            a1 = mfma16f(WhhF[1][0], bh0, a1);
            a3 = mfma16f(WhhF[2][0], bh0, a3);
            a0 = mfma16f(WhhF[0][1], bh1, a0);
            a1 = mfma16f(WhhF[1][1], bh1, a1);
            a3 = mfma16f(WhhF[2][1], bh1, a3);
            a0 = mfma16f(WhhF[0][2], bh2, a0);
            a1 = mfma16f(WhhF[1][2], bh2, a1);
            a3 = mfma16f(WhhF[2][2], bh2, a3);
            a0 = mfma16f(WhhF[0][3], bh3, a0);
            a1 = mfma16f(WhhF[1][3], bh3, a1);
            a3 = mfma16f(WhhF[2][3], bh3, a3);

            float psum = 0.0f;
            _Float16 h16[4];
            #pragma unroll
            for (int i = 0; i < 4; ++i) {
                float r  = __builtin_amdgcn_rcpf(1.0f + exp2_hw(-a0[i]));
                float z  = __builtin_amdgcn_rcpf(1.0f + exp2_hw(-a1[i]));
                float y  = fmaf(r, a3[i], a2[i]);
                float n  = fmaf(-2.0f,
                                __builtin_amdgcn_rcpf(1.0f + exp2_hw(y)), 1.0f);
                float hn = fmaf(z, h_old[i] - n, n);
                h_old[i] = hn;
                h16[i]   = (_Float16)hn;
                psum = fmaf(wout_r[i], hn, psum);
            }

            union { _Float16 h[4]; uint2 u; } hu;
            hu.h[0] = h16[0]; hu.h[1] = h16[1];
            hu.h[2] = h16[2]; hu.h[3] = h16[3];
            *(uint2*)&h_s[wb][bcol][wid * 16 + g4 * 4] = hu.u;

            psum += __shfl_xor(psum, 16);
            psum += __shfl_xor(psum, 32);
            if (lane < 16) ps_s[wb][lane][wid] = psum;

            if ((u & 1) == 0) {
                xf0 = pack_f16(sB0, sB1);
                xf1 = pack_f16(sB2, sB3);
            } else {
                xf0 = pack_f16(sA0, sA1);
                xf1 = pack_f16(sA2, sA3);
            }

            wg_barrier();
            rb = wb; wb = (wb == 2) ? 0 : wb + 1;
        }
    }

    if (outw) {
        f32x4 q0 = *(const f32x4*)&ps_s[2][lane][0];
        f32x4 q1 = *(const f32x4*)&ps_s[2][lane][4];
        float sm = (q0[0] + q0[1]) + (q0[2] + q0[3])
                 + (q1[0] + q1[1]) + (q1[2] + q1[3]);
        o3 = fast_tanh(sm + bout);
        *(float4*)(outp + (TSEQ - 4)) = make_float4(o0, o1, o2, o3);
    }
}

extern "C" void kernel_launch(void* const* d_in, const int* in_sizes, int n_in,
                              void* d_out, int out_size, void* d_ws, size_t ws_size,
                              hipStream_t stream) {
    const float* x     = (const float*)d_in[0];
    const float* W_ih  = (const float*)d_in[1];
    const float* W_hh  = (const float*)d_in[2];
    const float* b_ih  = (const float*)d_in[3];
    const float* b_hh  = (const float*)d_in[4];
    const float* W_out = (const float*)d_in[5];
    const float* b_out = (const float*)d_in[6];
    float* out = (float*)d_out;

    const size_t gi_bytes = (size_t)TSEQ * NB * 384 * sizeof(_Float16); // 201.3 MB
    const size_t pp_bytes = (size_t)TSEQ * 32 * NB * sizeof(float);     // 33.6 MB

    if (ws_size >= gi_bytes + pp_bytes) {
        uint2* gi = (uint2*)d_ws;
        float* pp = (float*)((char*)d_ws + gi_bytes);
        gi_gemm16<<<dim3(32, 32), 512, 0, stream>>>(x, W_ih, b_ih, b_hh, gi);
        gru_rec<<<32, 512, 0, stream>>>(W_hh, b_hh, W_out, gi, pp);
        out_final<<<TSEQ, NB, 0, stream>>>(pp, b_out, out);
    } else {
        gru_fb<<<32, 512, 0, stream>>>(x, W_ih, W_hh, b_ih, b_hh,
                                       W_out, b_out, out);
    }
}